// Round 2
// baseline (2230.943 us; speedup 1.0000x reference)
//
#include <hip/hip_runtime.h>
#include <cstdint>

#define DEV static __device__ __forceinline__

// ---------------- problem constants ----------------
constexpr int BATCH = 2;
constexpr int G0 = 80;                 // input grid
constexpr int D1 = 78, D2 = 76, D3 = 74;
constexpr int CIN = 4, C = 32;         // conv channels
constexpr int SD = 64, NSLOT = 8;      // slot dim, #slots
constexpr int D1S = D1 * D1 * D1;      // 474552
constexpr int D2S = D2 * D2 * D2;      // 438976
constexpr int D3S = D3 * D3 * D3;      // 405224
constexpr int NPOS1 = BATCH * D1S;     // 949104
constexpr int NPOS2 = BATCH * D2S;     // 877952
constexpr int NPOS3 = BATCH * D3S;     // 810448
constexpr int NBLK_ATTN = (D3S + 255) / 256;  // 1583

// ---------------- workspace layout (bytes) ----------------
// act1 (bf16 ch-last, 60.7MB) | act2 (bf16 ch-last, 56.2MB) | small (~0.25MB)
// feat (bf16, 51.9MB) overlays act1 (dead once conv2 done). Total ~112MB.
constexpr size_t A1_BYTES = (size_t)NPOS1 * C * 2;   // 60,742,656
constexpr size_t A2_BYTES = (size_t)NPOS2 * C * 2;   // 56,188,928
constexpr size_t S_OFF    = A1_BYTES + A2_BYTES;     // 116,931,584

DEV unsigned short f2bf(float f) {
  unsigned int u = __float_as_uint(f);
  u += 0x7fffu + ((u >> 16) & 1u);   // round-to-nearest-even
  return (unsigned short)(u >> 16);
}
DEV unsigned int pk2(float a, float b) {
  return (unsigned int)f2bf(a) | ((unsigned int)f2bf(b) << 16);
}
DEV float bflo(unsigned int u) { return __uint_as_float(u << 16); }
DEV float bfhi(unsigned int u) { return __uint_as_float(u & 0xffff0000u); }

// ---------------- weight transpose ----------------
// wt1[(ci*27+tap)*32+co] ; wt2/wt3[(tap*32+ci)*32+co]
__global__ __launch_bounds__(256) void k_wtr(const float* __restrict__ w1,
                                             const float* __restrict__ w2,
                                             const float* __restrict__ w3,
                                             float* __restrict__ wt1,
                                             float* __restrict__ wt2,
                                             float* __restrict__ wt3) {
  int idx = blockIdx.x * 256 + threadIdx.x;
  if (idx < 3456) {
    int t = idx >> 5, co = idx & 31;
    wt1[idx] = w1[co * 108 + t];
  }
  int i2 = idx - 3456;
  if (i2 >= 0 && i2 < 27648) {
    int co = i2 & 31, ci = (i2 >> 5) & 31, tap = i2 >> 10;
    wt2[i2] = w2[(co * 32 + ci) * 27 + tap];
  }
  int i3 = idx - 3456 - 27648;
  if (i3 >= 0 && i3 < 27648) {
    int co = i3 & 31, ci = (i3 >> 5) & 31, tap = i3 >> 10;
    wt3[i3] = w3[(co * 32 + ci) * 27 + tap];
  }
}

// ---------------- conv1: NCDHW fp32 in -> ch-last bf16 out, +ReLU ----------------
__global__ __launch_bounds__(256) void k_conv1(const float* __restrict__ in,
                                               const float* __restrict__ wt1,
                                               const float* __restrict__ bias,
                                               unsigned short* __restrict__ out) {
  int idx = blockIdx.x * 256 + threadIdx.x;
  if (idx >= NPOS1) return;
  int b = idx / D1S;
  int rem = idx % D1S;
  int z = rem / (D1 * D1);
  int y = (rem / D1) % D1;
  int x = rem % D1;
  float acc[C];
#pragma unroll
  for (int co = 0; co < C; co++) acc[co] = bias[co];
#pragma unroll 1
  for (int ci = 0; ci < CIN; ci++) {
    const float* ib = in + (size_t)(b * CIN + ci) * (G0 * G0 * G0);
#pragma unroll 1
    for (int dz = 0; dz < 3; dz++) {
#pragma unroll 1
      for (int dy = 0; dy < 3; dy++) {
        const float* ip = ib + (size_t)(z + dz) * (G0 * G0) + (size_t)(y + dy) * G0 + x;
        const float* wp = wt1 + (ci * 27 + dz * 9 + dy * 3) * C;
#pragma unroll
        for (int dx = 0; dx < 3; dx++) {
          float v = ip[dx];
          const float* w = wp + dx * C;
#pragma unroll
          for (int co = 0; co < C; co++) acc[co] = fmaf(v, w[co], acc[co]);
        }
      }
    }
  }
  unsigned short* op = out + (size_t)idx * C;
#pragma unroll
  for (int g = 0; g < 4; g++) {
    uint4 t;
    t.x = pk2(fmaxf(acc[g * 8 + 0], 0.f), fmaxf(acc[g * 8 + 1], 0.f));
    t.y = pk2(fmaxf(acc[g * 8 + 2], 0.f), fmaxf(acc[g * 8 + 3], 0.f));
    t.z = pk2(fmaxf(acc[g * 8 + 4], 0.f), fmaxf(acc[g * 8 + 5], 0.f));
    t.w = pk2(fmaxf(acc[g * 8 + 6], 0.f), fmaxf(acc[g * 8 + 7], 0.f));
    ((uint4*)op)[g] = t;
  }
}

// ---------------- shared conv body: one tap = 32ch bf16 in, 32 out FMAs ----------------
DEV void fma_tap(const uint4* __restrict__ ip, const float* __restrict__ wp, float acc[C]) {
#pragma unroll
  for (int g = 0; g < 4; g++) {
    uint4 raw = ip[g];
    unsigned int w4[4] = {raw.x, raw.y, raw.z, raw.w};
#pragma unroll
    for (int h = 0; h < 4; h++) {
      int ci = g * 8 + h * 2;
      float v0 = bflo(w4[h]);
      float v1 = bfhi(w4[h]);
      const float* w0 = wp + ci * C;
      const float* w1 = wp + (ci + 1) * C;
#pragma unroll
      for (int co = 0; co < C; co++) acc[co] = fmaf(v0, w0[co], acc[co]);
#pragma unroll
      for (int co = 0; co < C; co++) acc[co] = fmaf(v1, w1[co], acc[co]);
    }
  }
}

template <int DIN>
DEV void conv32(const unsigned short* __restrict__ ib, int z, int y, int x,
                const float* __restrict__ wt, float acc[C]) {
#pragma unroll 1
  for (int dz = 0; dz < 3; dz++) {
#pragma unroll 1
    for (int dy = 0; dy < 3; dy++) {
      const unsigned short* row =
          ib + ((size_t)(z + dz) * (DIN * DIN) + (size_t)(y + dy) * DIN + x) * C;
      const float* wp = wt + (dz * 9 + dy * 3) * (C * C);
#pragma unroll
      for (int dx = 0; dx < 3; dx++)
        fma_tap((const uint4*)(row + dx * C), wp + dx * (C * C), acc);
    }
  }
}

// ---------------- conv2: bf16 ch-last -> bf16 ch-last, +ReLU ----------------
__global__ __launch_bounds__(256) void k_conv2(const unsigned short* __restrict__ act1,
                                               const float* __restrict__ wt2,
                                               const float* __restrict__ bias,
                                               unsigned short* __restrict__ act2) {
  int idx = blockIdx.x * 256 + threadIdx.x;
  if (idx >= NPOS2) return;
  int b = idx / D2S;
  int rem = idx % D2S;
  int z = rem / (D2 * D2);
  int y = (rem / D2) % D2;
  int x = rem % D2;
  float acc[C];
#pragma unroll
  for (int co = 0; co < C; co++) acc[co] = bias[co];
  conv32<D1>(act1 + (size_t)b * D1S * C, z, y, x, wt2, acc);
  unsigned short* op = act2 + (size_t)idx * C;
#pragma unroll
  for (int g = 0; g < 4; g++) {
    uint4 t;
    t.x = pk2(fmaxf(acc[g * 8 + 0], 0.f), fmaxf(acc[g * 8 + 1], 0.f));
    t.y = pk2(fmaxf(acc[g * 8 + 2], 0.f), fmaxf(acc[g * 8 + 3], 0.f));
    t.z = pk2(fmaxf(acc[g * 8 + 4], 0.f), fmaxf(acc[g * 8 + 5], 0.f));
    t.w = pk2(fmaxf(acc[g * 8 + 6], 0.f), fmaxf(acc[g * 8 + 7], 0.f));
    ((uint4*)op)[g] = t;
  }
}

// ---------------- conv3 + ReLU + LayerNorm -> feat bf16 ----------------
__global__ __launch_bounds__(256) void k_conv3feat(const unsigned short* __restrict__ act2,
                                                   const float* __restrict__ wt3,
                                                   const float* __restrict__ bias,
                                                   const float* __restrict__ lng,
                                                   const float* __restrict__ lnb,
                                                   unsigned short* __restrict__ feat) {
  int idx = blockIdx.x * 256 + threadIdx.x;
  if (idx >= NPOS3) return;
  int b = idx / D3S;
  int rem = idx % D3S;
  int z = rem / (D3 * D3);
  int y = (rem / D3) % D3;
  int x = rem % D3;
  float acc[C];
#pragma unroll
  for (int co = 0; co < C; co++) acc[co] = bias[co];
  conv32<D2>(act2 + (size_t)b * D2S * C, z, y, x, wt3, acc);
  // ReLU + LayerNorm over 32 channels
  float s = 0.f, s2 = 0.f;
#pragma unroll
  for (int c = 0; c < C; c++) {
    float v = fmaxf(acc[c], 0.f);
    acc[c] = v; s += v; s2 += v * v;
  }
  float m = s * (1.f / C);
  float inv = rsqrtf(s2 * (1.f / C) - m * m + 1e-5f);
#pragma unroll
  for (int c = 0; c < C; c++) acc[c] = (acc[c] - m) * inv * lng[c] + lnb[c];
  unsigned short* op = feat + (size_t)idx * C;
#pragma unroll
  for (int g = 0; g < 4; g++) {
    uint4 t;
    t.x = pk2(acc[g * 8 + 0], acc[g * 8 + 1]);
    t.y = pk2(acc[g * 8 + 2], acc[g * 8 + 3]);
    t.z = pk2(acc[g * 8 + 4], acc[g * 8 + 5]);
    t.w = pk2(acc[g * 8 + 6], acc[g * 8 + 7]);
    ((uint4*)op)[g] = t;
  }
}

// ---------------- qprep: q = LN(slots)@qw^T ; qk = k_w^T q ; zero accumulators ----------------
__global__ __launch_bounds__(256) void k_qprep(const float* __restrict__ slots_src,
                                               const float* __restrict__ qlng,
                                               const float* __restrict__ qlnb,
                                               const float* __restrict__ qw,
                                               const float* __restrict__ kw,
                                               float* __restrict__ qk,
                                               float* __restrict__ upd_acc,
                                               float* __restrict__ rowsum) {
  __shared__ float ln_s[16][SD];
  __shared__ float q_s[16][SD];
  __shared__ float mv[16][2];
  int tid = threadIdx.x;
  for (int o = tid; o < 512; o += 256) upd_acc[o] = 0.f;
  if (tid < 16) {
    rowsum[tid] = 0.f;
    float s = 0.f, s2 = 0.f;
    for (int c = 0; c < SD; c++) { float v = slots_src[tid * SD + c]; s += v; s2 += v * v; }
    float m = s * (1.f / SD);
    mv[tid][0] = m;
    mv[tid][1] = rsqrtf(s2 * (1.f / SD) - m * m + 1e-5f);
  }
  __syncthreads();
  for (int idx = tid; idx < 16 * SD; idx += 256) {
    int r = idx >> 6, c = idx & 63;
    ln_s[r][c] = (slots_src[idx] - mv[r][0]) * mv[r][1] * qlng[c] + qlnb[c];
  }
  __syncthreads();
  for (int o = tid; o < 16 * SD; o += 256) {
    int r = o >> 6, d = o & 63;
    float s = 0.f;
    for (int c = 0; c < SD; c++) s = fmaf(ln_s[r][c], qw[d * SD + c], s);
    q_s[r][d] = s;
  }
  __syncthreads();
  // qk[r][c] = sum_d q[r][d] * k_w[d][c]   (k_w is [SD=64 out, C=32 in] row-major)
  for (int o = tid; o < 512; o += 256) {
    int r = o >> 5, c = o & 31;
    float s = 0.f;
    for (int d = 0; d < SD; d++) s = fmaf(q_s[r][d], kw[d * C + c], s);
    qk[o] = s;
  }
}

// ---------------- fused attention on feat: dots -> softmax(slots) -> attn·feat + rowsum ----------------
__global__ __launch_bounds__(256) void k_attn(const unsigned short* __restrict__ feat,
                                              const float* __restrict__ qk,
                                              float* __restrict__ upd_acc,
                                              float* __restrict__ rowsum,
                                              float* __restrict__ attn_out, int last) {
  __shared__ float f_s[256][33];     // +1 pad: phase-1 writes stride 33 -> conflict-free
  __shared__ float a_s[NSLOT][256];
  __shared__ float qk_s[256];
  int tid = threadIdx.x;
  int b = blockIdx.y;
  int j0 = blockIdx.x * 256;
  int j = j0 + tid;
  qk_s[tid] = qk[b * 256 + tid];
  bool valid = j < D3S;
  float f[C];
  if (valid) {
    const uint4* fp = (const uint4*)(feat + ((size_t)b * D3S + j) * C);
#pragma unroll
    for (int g = 0; g < 4; g++) {
      uint4 raw = fp[g];
      f[g * 8 + 0] = bflo(raw.x); f[g * 8 + 1] = bfhi(raw.x);
      f[g * 8 + 2] = bflo(raw.y); f[g * 8 + 3] = bfhi(raw.y);
      f[g * 8 + 4] = bflo(raw.z); f[g * 8 + 5] = bfhi(raw.z);
      f[g * 8 + 6] = bflo(raw.w); f[g * 8 + 7] = bfhi(raw.w);
    }
  } else {
#pragma unroll
    for (int c = 0; c < C; c++) f[c] = 0.f;
  }
#pragma unroll
  for (int c = 0; c < C; c++) f_s[tid][c] = f[c];
  __syncthreads();
  float dot[NSLOT];
#pragma unroll
  for (int i = 0; i < NSLOT; i++) dot[i] = 0.f;
#pragma unroll
  for (int c = 0; c < C; c++) {
    float fc = f[c];
#pragma unroll
    for (int i = 0; i < NSLOT; i++) dot[i] = fmaf(fc, qk_s[i * C + c], dot[i]);
  }
  float attn[NSLOT];
  if (valid) {
    float mx = -1e30f;
#pragma unroll
    for (int i = 0; i < NSLOT; i++) { dot[i] *= 0.125f; mx = fmaxf(mx, dot[i]); }
    float ssum = 0.f;
#pragma unroll
    for (int i = 0; i < NSLOT; i++) { float e = __expf(dot[i] - mx); attn[i] = e; ssum += e; }
    float invs = 1.f / ssum;
#pragma unroll
    for (int i = 0; i < NSLOT; i++) attn[i] = fmaf(attn[i], invs, 1e-8f);
  } else {
#pragma unroll
    for (int i = 0; i < NSLOT; i++) attn[i] = 0.f;
  }
#pragma unroll
  for (int i = 0; i < NSLOT; i++) a_s[i][tid] = attn[i];
  if (last && valid) {
#pragma unroll
    for (int i = 0; i < NSLOT; i++) attn_out[(size_t)(b * NSLOT + i) * D3S + j] = attn[i];
  }
  __syncthreads();
  // phase 2: 256 threads = 8 slots x 32 channels
  int i0 = tid >> 5;
  int c = tid & 31;
  int jlim = min(256, D3S - j0);
  float acc = 0.f, rs = 0.f;
#pragma unroll 4
  for (int jj = 0; jj < jlim; jj++) {
    float a = a_s[i0][jj];
    acc = fmaf(a, f_s[jj][c], acc);
    rs += a;
  }
  atomicAdd(&upd_acc[(b * NSLOT + i0) * C + c], acc);
  if (c == 0) atomicAdd(&rowsum[b * NSLOT + i0], rs);
}

// ---------------- final: updates = (attn·feat)·v_w^T / rowsum ; GRU ; LN ; MLP residual ----------------
__global__ __launch_bounds__(256) void k_final(const float* __restrict__ slots_src,
                                               const float* __restrict__ upd_acc,
                                               const float* __restrict__ rowsum,
                                               const float* __restrict__ vw,
                                               const float* __restrict__ wih,
                                               const float* __restrict__ whh,
                                               const float* __restrict__ bih,
                                               const float* __restrict__ bhh,
                                               const float* __restrict__ rlng,
                                               const float* __restrict__ rlnb,
                                               const float* __restrict__ w1,
                                               const float* __restrict__ rb1,
                                               const float* __restrict__ w2,
                                               const float* __restrict__ rb2,
                                               float* __restrict__ slots_dst,
                                               float* __restrict__ out_slots, int last) {
  __shared__ float updc[16][33], upd[16][64], hh[16][64], xg[16][192], hg[16][192];
  __shared__ float hn[16][64], tl[16][64], m1[16][128];
  __shared__ float mv[16][2];
  int tid = threadIdx.x;
  for (int o = tid; o < 512; o += 256) {
    int r = o >> 5, cc = o & 31;
    updc[r][cc] = upd_acc[o] / rowsum[r];
  }
  for (int idx = tid; idx < 1024; idx += 256) {
    int r = idx >> 6, dd = idx & 63;
    hh[r][dd] = slots_src[idx];
  }
  __syncthreads();
  for (int o = tid; o < 1024; o += 256) {
    int r = o >> 6, dd = o & 63;
    float s = 0.f;
    for (int cc = 0; cc < 32; cc++) s = fmaf(updc[r][cc], vw[dd * 32 + cc], s);
    upd[r][dd] = s;
  }
  __syncthreads();
  for (int o = tid; o < 6144; o += 256) {
    int sel = o >= 3072;
    int oo = o - sel * 3072;
    int r = oo / 192, cg = oo % 192;
    const float* sp = sel ? &hh[r][0] : &upd[r][0];
    const float* w = sel ? whh : wih;
    float s = sel ? bhh[cg] : bih[cg];
    for (int dd = 0; dd < 64; dd++) s = fmaf(sp[dd], w[cg * 64 + dd], s);
    float* dp = sel ? &hg[r][0] : &xg[r][0];
    dp[cg] = s;
  }
  __syncthreads();
  for (int idx = tid; idx < 1024; idx += 256) {
    int r = idx >> 6, dd = idx & 63;
    float rr = 1.f / (1.f + __expf(-(xg[r][dd] + hg[r][dd])));
    float zz = 1.f / (1.f + __expf(-(xg[r][64 + dd] + hg[r][64 + dd])));
    float nn = tanhf(xg[r][128 + dd] + rr * hg[r][128 + dd]);
    hn[r][dd] = (1.f - zz) * nn + zz * hh[r][dd];
  }
  __syncthreads();
  if (tid < 16) {
    float s = 0.f, s2 = 0.f;
    for (int cc = 0; cc < 64; cc++) { float v = hn[tid][cc]; s += v; s2 += v * v; }
    float m = s * (1.f / 64);
    mv[tid][0] = m;
    mv[tid][1] = rsqrtf(s2 * (1.f / 64) - m * m + 1e-5f);
  }
  __syncthreads();
  for (int idx = tid; idx < 1024; idx += 256) {
    int r = idx >> 6, dd = idx & 63;
    tl[r][dd] = (hn[r][dd] - mv[r][0]) * mv[r][1] * rlng[dd] + rlnb[dd];
  }
  __syncthreads();
  for (int o = tid; o < 2048; o += 256) {
    int r = o >> 7, jj = o & 127;
    float s = rb1[jj];
    for (int dd = 0; dd < 64; dd++) s = fmaf(tl[r][dd], w1[jj * 64 + dd], s);
    m1[r][jj] = fmaxf(s, 0.f);
  }
  __syncthreads();
  for (int idx = tid; idx < 1024; idx += 256) {
    int r = idx >> 6, dd = idx & 63;
    float s = rb2[dd];
    for (int jj = 0; jj < 128; jj++) s = fmaf(m1[r][jj], w2[dd * 128 + jj], s);
    float out = hn[r][dd] + s;
    slots_dst[idx] = out;
    if (last) out_slots[idx] = out;
  }
}

// ---------------- host launch ----------------
extern "C" void kernel_launch(void* const* d_in, const int* in_sizes, int n_in,
                              void* d_out, int out_size, void* d_ws, size_t ws_size,
                              hipStream_t stream) {
  const float* slots = (const float*)d_in[0];
  const float* oin   = (const float*)d_in[1];
  const float* w1    = (const float*)d_in[2];
  const float* b1    = (const float*)d_in[3];
  const float* w2    = (const float*)d_in[4];
  const float* b2    = (const float*)d_in[5];
  const float* w3    = (const float*)d_in[6];
  const float* b3    = (const float*)d_in[7];
  const float* kw    = (const float*)d_in[8];
  const float* vw    = (const float*)d_in[9];
  const float* qlng  = (const float*)d_in[10];
  const float* qlnb  = (const float*)d_in[11];
  const float* qw    = (const float*)d_in[12];
  const float* wih   = (const float*)d_in[13];
  const float* whh   = (const float*)d_in[14];
  const float* bih   = (const float*)d_in[15];
  const float* bhh   = (const float*)d_in[16];
  const float* rlng  = (const float*)d_in[17];
  const float* rlnb  = (const float*)d_in[18];
  const float* rw1   = (const float*)d_in[19];
  const float* rb1   = (const float*)d_in[20];
  const float* rw2   = (const float*)d_in[21];
  const float* rb2   = (const float*)d_in[22];
  const float* flng  = (const float*)d_in[23];
  const float* flnb  = (const float*)d_in[24];

  char* ws = (char*)d_ws;
  unsigned short* act1 = (unsigned short*)ws;
  unsigned short* act2 = (unsigned short*)(ws + A1_BYTES);
  unsigned short* feat = act1;  // overlay: act1 dead once conv2 completes
  float* sm   = (float*)(ws + S_OFF);
  float* wt1  = sm;                    // 3456 (pad 4096)
  float* wt2  = wt1 + 4096;            // 27648
  float* wt3  = wt2 + 27648;           // 27648
  float* qk   = wt3 + 27648;           // 512
  float* upd  = qk + 512;              // 512
  float* rsum = upd + 512;             // 16 (pad 64)
  float* sl0  = rsum + 64;             // 1024
  float* sl1  = sl0 + 1024;            // 1024

  float* out_slots = (float*)d_out;
  float* attn_out  = (float*)d_out + 1024;

  k_wtr<<<230, 256, 0, stream>>>(w1, w2, w3, wt1, wt2, wt3);
  k_conv1<<<(NPOS1 + 255) / 256, 256, 0, stream>>>(oin, wt1, b1, act1);
  k_conv2<<<(NPOS2 + 255) / 256, 256, 0, stream>>>(act1, wt2, b2, act2);
  k_conv3feat<<<(NPOS3 + 255) / 256, 256, 0, stream>>>(act2, wt3, b3, flng, flnb, feat);

  const float* src = slots;
  float* dst = sl0;
  for (int it = 0; it < 3; it++) {
    int last = (it == 2);
    k_qprep<<<1, 256, 0, stream>>>(src, qlng, qlnb, qw, kw, qk, upd, rsum);
    k_attn<<<dim3(NBLK_ATTN, BATCH), 256, 0, stream>>>(feat, qk, upd, rsum, attn_out, last);
    k_final<<<1, 256, 0, stream>>>(src, upd, rsum, vw, wih, whh, bih, bhh,
                                   rlng, rlnb, rw1, rb1, rw2, rb2, dst, out_slots, last);
    src = dst;
    dst = (it == 0) ? sl1 : sl0;
  }
}

// Round 3
// 851.741 us; speedup vs baseline: 2.6193x; 2.6193x over previous
//
#include <hip/hip_runtime.h>
#include <cstdint>

#define DEV static __device__ __forceinline__

typedef __attribute__((ext_vector_type(8))) short bf16x8;
typedef __attribute__((ext_vector_type(4))) float f32x4;

// ---------------- problem constants ----------------
constexpr int BATCH = 2;
constexpr int G0 = 80;
constexpr int D1 = 78, D2 = 76, D3 = 74;
constexpr int CIN = 4, C = 32;
constexpr int SD = 64, NSLOT = 8;
constexpr int D1S = D1 * D1 * D1;      // 474552
constexpr int D2S = D2 * D2 * D2;      // 438976
constexpr int D3S = D3 * D3 * D3;      // 405224
constexpr int NPOS1 = BATCH * D1S;
constexpr int NCHUNK = (D3S + 255) / 256;   // 1583
constexpr int ATTN_GX = 396;                // chunk-strided blocks per batch

// ---------------- workspace layout (bytes) ----------------
constexpr size_t A1_BYTES = (size_t)NPOS1 * C * 2;           // 60.7 MB
constexpr size_t A2_BYTES = (size_t)BATCH * D2S * C * 2;     // 56.2 MB
constexpr size_t S_OFF    = A1_BYTES + A2_BYTES;             // ~117 MB

DEV unsigned short f2bf(float f) {
  unsigned int u = __float_as_uint(f);
  u += 0x7fffu + ((u >> 16) & 1u);
  return (unsigned short)(u >> 16);
}
DEV unsigned int pk2(float a, float b) {
  return (unsigned int)f2bf(a) | ((unsigned int)f2bf(b) << 16);
}
DEV float bflo(unsigned int u) { return __uint_as_float(u << 16); }
DEV float bfhi(unsigned int u) { return __uint_as_float(u & 0xffff0000u); }

// ---------------- weight prep ----------------
// wt1 fp32 [(ci*27+tap)*32+co] for conv1; wB2/wB3 bf16 [tap][co][ci] for MFMA convs
__global__ __launch_bounds__(256) void k_wtr(const float* __restrict__ w1,
                                             const float* __restrict__ w2,
                                             const float* __restrict__ w3,
                                             float* __restrict__ wt1,
                                             unsigned short* __restrict__ wB2,
                                             unsigned short* __restrict__ wB3) {
  int idx = blockIdx.x * 256 + threadIdx.x;
  if (idx < 3456) {
    int t = idx >> 5, co = idx & 31;
    wt1[idx] = w1[co * 108 + t];
  }
  int i2 = idx - 3456;
  if (i2 >= 0 && i2 < 27648) {
    int ci = i2 & 31, co = (i2 >> 5) & 31, tap = i2 >> 10;
    wB2[i2] = f2bf(w2[(co * 32 + ci) * 27 + tap]);
  }
  int i3 = idx - 3456 - 27648;
  if (i3 >= 0 && i3 < 27648) {
    int ci = i3 & 31, co = (i3 >> 5) & 31, tap = i3 >> 10;
    wB3[i3] = f2bf(w3[(co * 32 + ci) * 27 + tap]);
  }
}

// ---------------- conv1: NCDHW fp32 in -> ch-last bf16 out, +ReLU (scalar; only 6.6 GF) ----------------
__global__ __launch_bounds__(256) void k_conv1(const float* __restrict__ in,
                                               const float* __restrict__ wt1,
                                               const float* __restrict__ bias,
                                               unsigned short* __restrict__ out) {
  int idx = blockIdx.x * 256 + threadIdx.x;
  if (idx >= NPOS1) return;
  int b = idx / D1S;
  int rem = idx % D1S;
  int z = rem / (D1 * D1);
  int y = (rem / D1) % D1;
  int x = rem % D1;
  float acc[C];
#pragma unroll
  for (int co = 0; co < C; co++) acc[co] = bias[co];
#pragma unroll 1
  for (int ci = 0; ci < CIN; ci++) {
    const float* ib = in + (size_t)(b * CIN + ci) * (G0 * G0 * G0);
#pragma unroll 1
    for (int dz = 0; dz < 3; dz++) {
#pragma unroll 1
      for (int dy = 0; dy < 3; dy++) {
        const float* ip = ib + (size_t)(z + dz) * (G0 * G0) + (size_t)(y + dy) * G0 + x;
        const float* wp = wt1 + (ci * 27 + dz * 9 + dy * 3) * C;
#pragma unroll
        for (int dx = 0; dx < 3; dx++) {
          float v = ip[dx];
          const float* w = wp + dx * C;
#pragma unroll
          for (int co = 0; co < C; co++) acc[co] = fmaf(v, w[co], acc[co]);
        }
      }
    }
  }
  unsigned short* op = out + (size_t)idx * C;
#pragma unroll
  for (int g = 0; g < 4; g++) {
    uint4 t;
    t.x = pk2(fmaxf(acc[g * 8 + 0], 0.f), fmaxf(acc[g * 8 + 1], 0.f));
    t.y = pk2(fmaxf(acc[g * 8 + 2], 0.f), fmaxf(acc[g * 8 + 3], 0.f));
    t.z = pk2(fmaxf(acc[g * 8 + 4], 0.f), fmaxf(acc[g * 8 + 5], 0.f));
    t.w = pk2(fmaxf(acc[g * 8 + 6], 0.f), fmaxf(acc[g * 8 + 7], 0.f));
    ((uint4*)op)[g] = t;
  }
}

// ---------------- MFMA implicit-GEMM conv: 16x4x4 output tile, 32 cout, K=27 taps x 32 cin ----------------
// A-frag (16x16x32): lane holds A[m=lane&15][k=q*8+j]  (m = x within row, k = cin)
// B-frag:            lane holds B[k=q*8+j][n=lane&15]  (n = cout; wB[tap][co][ci] is 8-contig in ci)
// D:                 lane,reg -> D[m=q*4+reg][n=lane&15]   (m89/m91-verified mappings)
template <int DIN, int DOUT, bool DO_LN>
__global__ __launch_bounds__(256) void k_convm(const unsigned short* __restrict__ actin,
                                               const unsigned short* __restrict__ wB,
                                               const float* __restrict__ bias,
                                               const float* __restrict__ lng,
                                               const float* __restrict__ lnb,
                                               unsigned short* __restrict__ actout) {
  constexpr int DIN2 = DIN * DIN;
  constexpr size_t DINS = (size_t)DIN * DIN2;
  constexpr int DOUT2 = DOUT * DOUT;
  constexpr size_t DOUTS = (size_t)DOUT * DOUT2;
  constexpr int NX = (DOUT + 15) / 16, NY = (DOUT + 3) / 4, NZ = (DOUT + 3) / 4;

  __shared__ alignas(16) unsigned short s_halo[648 * 32];   // 18x6x6 pos x 32ch bf16 = 41472 B

  int bid = blockIdx.x;
  int b = bid / (NX * NY * NZ);
  int t = bid % (NX * NY * NZ);
  int tx = t % NX;
  int t2 = t / NX;
  int ty = t2 % NY;
  int tz = t2 / NY;
  int x0 = tx * 16, y0 = ty * 4, z0 = tz * 4;
  const unsigned short* ib = actin + (size_t)b * DINS * 32;

  int tid = threadIdx.x;
  // stage halo (clamped reads only feed masked outputs)
  for (int ck = tid; ck < 2592; ck += 256) {
    int pos = ck >> 2, sub = ck & 3;
    int xl = pos % 18;
    int p2 = pos / 18;
    int yl = p2 % 6;
    int zl = p2 / 6;
    int xg = min(x0 + xl, DIN - 1);
    int yg = min(y0 + yl, DIN - 1);
    int zg = min(z0 + zl, DIN - 1);
    uint4 v = *(const uint4*)(ib + ((size_t)zg * DIN2 + (size_t)yg * DIN + xg) * 32 + sub * 8);
    *(uint4*)(s_halo + pos * 32 + sub * 8) = v;
  }
  __syncthreads();

  int wv = tid >> 6;       // wave id = output z within tile
  int ln = tid & 63;
  int q = ln >> 4;
  int mr = ln & 15;

  f32x4 acc[4][2];
#pragma unroll
  for (int mi = 0; mi < 4; mi++)
#pragma unroll
    for (int nt = 0; nt < 2; nt++) acc[mi][nt] = (f32x4){0.f, 0.f, 0.f, 0.f};

#pragma unroll
  for (int dz = 0; dz < 3; dz++) {
#pragma unroll
    for (int dy = 0; dy < 3; dy++) {
#pragma unroll
      for (int dx = 0; dx < 3; dx++) {
        int tap = dz * 9 + dy * 3 + dx;
        bf16x8 B0 = *(const bf16x8*)(wB + tap * 1024 + mr * 32 + q * 8);
        bf16x8 B1 = *(const bf16x8*)(wB + tap * 1024 + (16 + mr) * 32 + q * 8);
#pragma unroll
        for (int mi = 0; mi < 4; mi++) {
          bf16x8 Af = *(const bf16x8*)(s_halo +
              ((wv + dz) * 108 + (mi + dy) * 18 + (mr + dx)) * 32 + q * 8);
          acc[mi][0] = __builtin_amdgcn_mfma_f32_16x16x32_bf16(Af, B0, acc[mi][0], 0, 0, 0);
          acc[mi][1] = __builtin_amdgcn_mfma_f32_16x16x32_bf16(Af, B1, acc[mi][1], 0, 0, 0);
        }
      }
    }
  }

  __syncthreads();                       // all A-reads done; reuse LDS for transpose
  float* s_out = (float*)s_halo;         // [256][33] = 33792 floats
#pragma unroll
  for (int mi = 0; mi < 4; mi++) {
    int mtile = wv * 4 + mi;             // z = wv, y = mi
#pragma unroll
    for (int nt = 0; nt < 2; nt++) {
#pragma unroll
      for (int r = 0; r < 4; r++) {
        int pl = mtile * 16 + q * 4 + r;
        s_out[pl * 33 + nt * 16 + mr] = acc[mi][nt][r];
      }
    }
  }
  __syncthreads();

  // epilogue: thread = one output position
  int xl = tid & 15, yl = (tid >> 4) & 3, zl = tid >> 6;
  int xg = x0 + xl, yg = y0 + yl, zg = z0 + zl;
  bool valid = (xg < DOUT) && (yg < DOUT) && (zg < DOUT);
  float v[C];
  float s = 0.f, s2 = 0.f;
#pragma unroll
  for (int c = 0; c < C; c++) {
    float x = fmaxf(s_out[tid * 33 + c] + bias[c], 0.f);
    v[c] = x;
    s += x; s2 += x * x;
  }
  if (DO_LN) {
    float m = s * (1.f / C);
    float inv = rsqrtf(s2 * (1.f / C) - m * m + 1e-5f);
#pragma unroll
    for (int c = 0; c < C; c++) v[c] = (v[c] - m) * inv * lng[c] + lnb[c];
  }
  if (valid) {
    unsigned short* op = actout + ((size_t)b * DOUTS + (size_t)zg * DOUT2 + (size_t)yg * DOUT + xg) * 32;
#pragma unroll
    for (int g = 0; g < 4; g++) {
      uint4 o;
      o.x = pk2(v[g * 8 + 0], v[g * 8 + 1]);
      o.y = pk2(v[g * 8 + 2], v[g * 8 + 3]);
      o.z = pk2(v[g * 8 + 4], v[g * 8 + 5]);
      o.w = pk2(v[g * 8 + 6], v[g * 8 + 7]);
      ((uint4*)op)[g] = o;
    }
  }
}

// ---------------- initial qprep: q = LN(slots)@qw^T ; qk = k_w^T q ; zero accumulators ----------------
__global__ __launch_bounds__(256) void k_qprep(const float* __restrict__ slots_src,
                                               const float* __restrict__ qlng,
                                               const float* __restrict__ qlnb,
                                               const float* __restrict__ qw,
                                               const float* __restrict__ kw,
                                               float* __restrict__ qk,
                                               float* __restrict__ upd_acc,
                                               float* __restrict__ rowsum) {
  __shared__ float ln_s[16][SD];
  __shared__ float q_s[16][SD];
  __shared__ float mv[16][2];
  int tid = threadIdx.x;
  for (int o = tid; o < 512; o += 256) upd_acc[o] = 0.f;
  if (tid < 16) {
    rowsum[tid] = 0.f;
    float s = 0.f, s2 = 0.f;
    for (int c = 0; c < SD; c++) { float v = slots_src[tid * SD + c]; s += v; s2 += v * v; }
    float m = s * (1.f / SD);
    mv[tid][0] = m;
    mv[tid][1] = rsqrtf(s2 * (1.f / SD) - m * m + 1e-5f);
  }
  __syncthreads();
  for (int idx = tid; idx < 16 * SD; idx += 256) {
    int r = idx >> 6, c = idx & 63;
    ln_s[r][c] = (slots_src[idx] - mv[r][0]) * mv[r][1] * qlng[c] + qlnb[c];
  }
  __syncthreads();
  for (int o = tid; o < 16 * SD; o += 256) {
    int r = o >> 6, d = o & 63;
    float s = 0.f;
    for (int c = 0; c < SD; c++) s = fmaf(ln_s[r][c], qw[d * SD + c], s);
    q_s[r][d] = s;
  }
  __syncthreads();
  for (int o = tid; o < 512; o += 256) {
    int r = o >> 5, c = o & 31;
    float s = 0.f;
    for (int d = 0; d < SD; d++) s = fmaf(q_s[r][d], kw[d * C + c], s);
    qk[o] = s;
  }
}

// ---------------- fused attention: chunk-strided, register accumulation, 1 atomic/thread ----------------
__global__ __launch_bounds__(256) void k_attn(const unsigned short* __restrict__ feat,
                                              const float* __restrict__ qk,
                                              float* __restrict__ upd_acc,
                                              float* __restrict__ rowsum,
                                              float* __restrict__ attn_out, int last) {
  __shared__ float f_s[256][33];
  __shared__ float a_s[NSLOT][256];
  __shared__ float qk_s[256];
  int tid = threadIdx.x;
  int b = blockIdx.y;
  qk_s[tid] = qk[b * 256 + tid];
  int i0 = tid >> 5;
  int cch = tid & 31;
  float accr = 0.f, rs = 0.f;

  for (int ch = blockIdx.x; ch < NCHUNK; ch += ATTN_GX) {
    int j0 = ch * 256;
    int j = j0 + tid;
    bool valid = j < D3S;
    float f[C];
    if (valid) {
      const uint4* fp = (const uint4*)(feat + ((size_t)b * D3S + j) * C);
#pragma unroll
      for (int g = 0; g < 4; g++) {
        uint4 raw = fp[g];
        f[g * 8 + 0] = bflo(raw.x); f[g * 8 + 1] = bfhi(raw.x);
        f[g * 8 + 2] = bflo(raw.y); f[g * 8 + 3] = bfhi(raw.y);
        f[g * 8 + 4] = bflo(raw.z); f[g * 8 + 5] = bfhi(raw.z);
        f[g * 8 + 6] = bflo(raw.w); f[g * 8 + 7] = bfhi(raw.w);
      }
    } else {
#pragma unroll
      for (int c = 0; c < C; c++) f[c] = 0.f;
    }
#pragma unroll
    for (int c = 0; c < C; c++) f_s[tid][c] = f[c];
    float dot[NSLOT];
#pragma unroll
    for (int i = 0; i < NSLOT; i++) dot[i] = 0.f;
#pragma unroll
    for (int c = 0; c < C; c++) {
      float fc = f[c];
#pragma unroll
      for (int i = 0; i < NSLOT; i++) dot[i] = fmaf(fc, qk_s[i * C + c], dot[i]);
    }
    float attn[NSLOT];
    if (valid) {
      float mx = -1e30f;
#pragma unroll
      for (int i = 0; i < NSLOT; i++) { dot[i] *= 0.125f; mx = fmaxf(mx, dot[i]); }
      float ssum = 0.f;
#pragma unroll
      for (int i = 0; i < NSLOT; i++) { float e = __expf(dot[i] - mx); attn[i] = e; ssum += e; }
      float invs = 1.f / ssum;
#pragma unroll
      for (int i = 0; i < NSLOT; i++) attn[i] = fmaf(attn[i], invs, 1e-8f);
    } else {
#pragma unroll
      for (int i = 0; i < NSLOT; i++) attn[i] = 0.f;
    }
#pragma unroll
    for (int i = 0; i < NSLOT; i++) a_s[i][tid] = attn[i];
    if (last && valid) {
#pragma unroll
      for (int i = 0; i < NSLOT; i++) attn_out[(size_t)(b * NSLOT + i) * D3S + j] = attn[i];
    }
    __syncthreads();
    int jlim = min(256, D3S - j0);
#pragma unroll 4
    for (int jj = 0; jj < jlim; jj++) {
      float a = a_s[i0][jj];
      accr = fmaf(a, f_s[jj][cch], accr);
      rs += a;
    }
    __syncthreads();
  }
  atomicAdd(&upd_acc[(b * NSLOT + i0) * C + cch], accr);
  if (cch == 0) atomicAdd(&rowsum[b * NSLOT + i0], rs);
}

// ---------------- final: v_w proj + GRU + LN + MLP residual + next-iter qprep ----------------
__global__ __launch_bounds__(256) void k_final(const float* __restrict__ slots_src,
                                               const float* __restrict__ upd_g,
                                               const float* __restrict__ rowsum,
                                               const float* __restrict__ vw,
                                               const float* __restrict__ wih,
                                               const float* __restrict__ whh,
                                               const float* __restrict__ bih,
                                               const float* __restrict__ bhh,
                                               const float* __restrict__ rlng,
                                               const float* __restrict__ rlnb,
                                               const float* __restrict__ w1,
                                               const float* __restrict__ rb1,
                                               const float* __restrict__ w2,
                                               const float* __restrict__ rb2,
                                               const float* __restrict__ qlng,
                                               const float* __restrict__ qlnb,
                                               const float* __restrict__ qw,
                                               const float* __restrict__ kw,
                                               float* __restrict__ qk_out,
                                               float* __restrict__ upd_z,
                                               float* __restrict__ rsum_z,
                                               float* __restrict__ slots_dst,
                                               float* __restrict__ out_slots, int last) {
  __shared__ float updc[16][33], upd_s[16][64], hh[16][64], xg[16][192], hg[16][192];
  __shared__ float hn[16][64], tl[16][64], m1[16][128];
  __shared__ float mv[16][2];
  int tid = threadIdx.x;
  for (int o = tid; o < 512; o += 256) {
    int r = o >> 5, cc = o & 31;
    updc[r][cc] = upd_g[o] / rowsum[r];
  }
  for (int idx = tid; idx < 1024; idx += 256) {
    int r = idx >> 6, dd = idx & 63;
    hh[r][dd] = slots_src[idx];
  }
  __syncthreads();
  for (int o = tid; o < 1024; o += 256) {
    int r = o >> 6, dd = o & 63;
    float s = 0.f;
    for (int cc = 0; cc < 32; cc++) s = fmaf(updc[r][cc], vw[dd * 32 + cc], s);
    upd_s[r][dd] = s;
  }
  __syncthreads();
  for (int o = tid; o < 6144; o += 256) {
    int sel = o >= 3072;
    int oo = o - sel * 3072;
    int r = oo / 192, cg = oo % 192;
    const float* sp = sel ? &hh[r][0] : &upd_s[r][0];
    const float* w = sel ? whh : wih;
    float s = sel ? bhh[cg] : bih[cg];
    for (int dd = 0; dd < 64; dd++) s = fmaf(sp[dd], w[cg * 64 + dd], s);
    float* dp = sel ? &hg[r][0] : &xg[r][0];
    dp[cg] = s;
  }
  __syncthreads();
  for (int idx = tid; idx < 1024; idx += 256) {
    int r = idx >> 6, dd = idx & 63;
    float rr = 1.f / (1.f + __expf(-(xg[r][dd] + hg[r][dd])));
    float zz = 1.f / (1.f + __expf(-(xg[r][64 + dd] + hg[r][64 + dd])));
    float nn = tanhf(xg[r][128 + dd] + rr * hg[r][128 + dd]);
    hn[r][dd] = (1.f - zz) * nn + zz * hh[r][dd];
  }
  __syncthreads();
  if (tid < 16) {
    float s = 0.f, s2 = 0.f;
    for (int cc = 0; cc < 64; cc++) { float v = hn[tid][cc]; s += v; s2 += v * v; }
    float m = s * (1.f / 64);
    mv[tid][0] = m;
    mv[tid][1] = rsqrtf(s2 * (1.f / 64) - m * m + 1e-5f);
  }
  __syncthreads();
  for (int idx = tid; idx < 1024; idx += 256) {
    int r = idx >> 6, dd = idx & 63;
    tl[r][dd] = (hn[r][dd] - mv[r][0]) * mv[r][1] * rlng[dd] + rlnb[dd];
  }
  __syncthreads();
  for (int o = tid; o < 2048; o += 256) {
    int r = o >> 7, jj = o & 127;
    float s = rb1[jj];
    for (int dd = 0; dd < 64; dd++) s = fmaf(tl[r][dd], w1[jj * 64 + dd], s);
    m1[r][jj] = fmaxf(s, 0.f);
  }
  __syncthreads();
  for (int idx = tid; idx < 1024; idx += 256) {
    int r = idx >> 6, dd = idx & 63;
    float s = rb2[dd];
    for (int jj = 0; jj < 128; jj++) s = fmaf(m1[r][jj], w2[dd * 128 + jj], s);
    float out = hn[r][dd] + s;
    slots_dst[idx] = out;
    hh[r][dd] = out;                 // snew for next-iter qprep
    if (last) out_slots[idx] = out;
  }
  __syncthreads();
  // ----- next-iteration qprep (fused) -----
  if (tid < 16) {
    float s = 0.f, s2 = 0.f;
    for (int cc = 0; cc < 64; cc++) { float v = hh[tid][cc]; s += v; s2 += v * v; }
    float m = s * (1.f / 64);
    mv[tid][0] = m;
    mv[tid][1] = rsqrtf(s2 * (1.f / 64) - m * m + 1e-5f);
  }
  __syncthreads();
  for (int idx = tid; idx < 1024; idx += 256) {
    int r = idx >> 6, dd = idx & 63;
    tl[r][dd] = (hh[r][dd] - mv[r][0]) * mv[r][1] * qlng[dd] + qlnb[dd];
  }
  __syncthreads();
  for (int o = tid; o < 1024; o += 256) {
    int r = o >> 6, d = o & 63;
    float s = 0.f;
    for (int cc = 0; cc < 64; cc++) s = fmaf(tl[r][cc], qw[d * 64 + cc], s);
    upd_s[r][d] = s;                 // q
  }
  __syncthreads();
  for (int o = tid; o < 512; o += 256) {
    int r = o >> 5, cc = o & 31;
    float s = 0.f;
    for (int d = 0; d < 64; d++) s = fmaf(upd_s[r][d], kw[d * 32 + cc], s);
    qk_out[o] = s;
    upd_z[o] = 0.f;
  }
  if (tid < 16) rsum_z[tid] = 0.f;
}

// ---------------- host launch ----------------
extern "C" void kernel_launch(void* const* d_in, const int* in_sizes, int n_in,
                              void* d_out, int out_size, void* d_ws, size_t ws_size,
                              hipStream_t stream) {
  const float* slots = (const float*)d_in[0];
  const float* oin   = (const float*)d_in[1];
  const float* w1    = (const float*)d_in[2];
  const float* b1    = (const float*)d_in[3];
  const float* w2    = (const float*)d_in[4];
  const float* b2    = (const float*)d_in[5];
  const float* w3    = (const float*)d_in[6];
  const float* b3    = (const float*)d_in[7];
  const float* kw    = (const float*)d_in[8];
  const float* vw    = (const float*)d_in[9];
  const float* qlng  = (const float*)d_in[10];
  const float* qlnb  = (const float*)d_in[11];
  const float* qw    = (const float*)d_in[12];
  const float* wih   = (const float*)d_in[13];
  const float* whh   = (const float*)d_in[14];
  const float* bih   = (const float*)d_in[15];
  const float* bhh   = (const float*)d_in[16];
  const float* rlng  = (const float*)d_in[17];
  const float* rlnb  = (const float*)d_in[18];
  const float* rw1   = (const float*)d_in[19];
  const float* rb1   = (const float*)d_in[20];
  const float* rw2   = (const float*)d_in[21];
  const float* rb2   = (const float*)d_in[22];
  const float* flng  = (const float*)d_in[23];
  const float* flnb  = (const float*)d_in[24];

  char* ws = (char*)d_ws;
  unsigned short* act1 = (unsigned short*)ws;
  unsigned short* act2 = (unsigned short*)(ws + A1_BYTES);
  unsigned short* feat = act1;   // overlay: act1 dead once conv2 completes
  float* wt1 = (float*)(ws + S_OFF);              // 4096 f
  unsigned short* wB2 = (unsigned short*)(wt1 + 4096);  // 27648 bf16
  unsigned short* wB3 = wB2 + 27648;                    // 27648 bf16
  float* qk   = (float*)(wB3 + 27648);
  float* upd  = qk + 512;
  float* rsum = upd + 512;       // 16 (pad 64)
  float* sl0  = rsum + 64;
  float* sl1  = sl0 + 1024;

  float* out_slots = (float*)d_out;
  float* attn_out  = (float*)d_out + 1024;

  k_wtr<<<230, 256, 0, stream>>>(w1, w2, w3, wt1, wB2, wB3);
  k_conv1<<<(NPOS1 + 255) / 256, 256, 0, stream>>>(oin, wt1, b1, act1);
  {
    constexpr int NB2 = ((D2 + 15) / 16) * ((D2 + 3) / 4) * ((D2 + 3) / 4) * BATCH;  // 3610
    k_convm<D1, D2, false><<<NB2, 256, 0, stream>>>(act1, wB2, b2, nullptr, nullptr, act2);
  }
  {
    constexpr int NB3 = ((D3 + 15) / 16) * ((D3 + 3) / 4) * ((D3 + 3) / 4) * BATCH;  // 3610
    k_convm<D2, D3, true><<<NB3, 256, 0, stream>>>(act2, wB3, b3, flng, flnb, feat);
  }

  k_qprep<<<1, 256, 0, stream>>>(slots, qlng, qlnb, qw, kw, qk, upd, rsum);
  const float* src = slots;
  float* dst = sl0;
  for (int it = 0; it < 3; it++) {
    int last = (it == 2);
    k_attn<<<dim3(ATTN_GX, BATCH), 256, 0, stream>>>(feat, qk, upd, rsum, attn_out, last);
    k_final<<<1, 256, 0, stream>>>(src, upd, rsum, vw, wih, whh, bih, bhh,
                                   rlng, rlnb, rw1, rb1, rw2, rb2,
                                   qlng, qlnb, qw, kw, qk, upd, rsum,
                                   dst, out_slots, last);
    src = dst;
    dst = (it == 0) ? sl1 : sl0;
  }
}